// Round 1
// baseline (117.209 us; speedup 1.0000x reference)
//
#include <hip/hip_runtime.h>

#define BT 128  // threads per block (2 waves)

__global__ __launch_bounds__(BT) void vin_kernel(
    const float* __restrict__ obs,
    const float* __restrict__ PhiW,
    const float* __restrict__ Phib,
    const float* __restrict__ LW,
    const float* __restrict__ Lb,
    float* __restrict__ out, int Btot)
{
    // Per-thread private LDS row for the dynamic 3x3 gathers.
    // stride 49 words (odd) -> at most 2-way bank aliasing (free on CDNA4).
    __shared__ float lds[BT * 49];
    const int tid = threadIdx.x;
    const int b = blockIdx.x * BT + tid;
    if (b >= Btot) return;  // no barriers anywhere -> early return is safe

    // ---- load obs row: 48 f32, 12x float4 ----
    float o[48];
    {
        const float4* g4 = reinterpret_cast<const float4*>(obs + (size_t)b * 48);
        #pragma unroll
        for (int q = 0; q < 12; ++q) {
            float4 t = g4[q];
            o[4*q+0] = t.x; o[4*q+1] = t.y; o[4*q+2] = t.z; o[4*q+3] = t.w;
        }
    }

    // ---- agent index: first nonzero of channel 1, default 5 ----
    int idx = 5;
    #pragma unroll
    for (int k = 15; k >= 0; --k)
        if (o[k*3+1] != 0.0f) idx = k;
    const int ai = idx >> 2;   // row (H index)
    const int aj = idx & 3;    // col (W index)

    // ---- stash obs row in LDS (needed later for dynamic window gather) ----
    float* my = &lds[tid * 49];
    #pragma unroll
    for (int k = 0; k < 48; ++k) my[k] = o[k];

    // ---- Phi matmul: ro[j] = sum_k o[k] * PhiW[j*48+k] + Phib[j] ----
    // PhiW/Phib indices are uniform -> scalar loads (broadcast).
    float ro[48];
    #pragma unroll
    for (int j = 0; j < 48; ++j) {
        float acc = Phib[j];
        #pragma unroll
        for (int k = 0; k < 48; ++k)
            acc = fmaf(o[k], PhiW[j*48 + k], acc);
        ro[j] = acc;
    }
    // o[] is dead from here on (its LDS copy serves the gather).

    // ---- logit accumulators + sub_state contribution (features 0..26) ----
    float lg0 = Lb[0], lg1 = Lb[1], lg2 = Lb[2], lg3 = Lb[3];
    #pragma unroll
    for (int dh = 0; dh < 3; ++dh) {
        #pragma unroll
        for (int dw = 0; dw < 3; ++dw) {
            int r = ai + dh - 1, c = aj + dw - 1;
            bool ok = ((unsigned)r < 4u) && ((unsigned)c < 4u);
            int ba = ok ? (r*4 + c) * 3 : 0;
            float s0 = my[ba+0], s1 = my[ba+1], s2 = my[ba+2];
            if (!ok) { s0 = 0.0f; s1 = 0.0f; s2 = 0.0f; }
            int f = (dh*3 + dw) * 3;
            lg0 = fmaf(s0, LW[0*36+f], fmaf(s1, LW[0*36+f+1], fmaf(s2, LW[0*36+f+2], lg0)));
            lg1 = fmaf(s0, LW[1*36+f], fmaf(s1, LW[1*36+f+1], fmaf(s2, LW[1*36+f+2], lg1)));
            lg2 = fmaf(s0, LW[2*36+f], fmaf(s1, LW[2*36+f+1], fmaf(s2, LW[2*36+f+2], lg2)));
            lg3 = fmaf(s0, LW[3*36+f], fmaf(s1, LW[3*36+f+1], fmaf(s2, LW[3*36+f+2], lg3)));
        }
    }

    // ---- VI constants: p, and per-direction (rin_neighbor - rout) ----
    // OFFSETS (wo,ho): (0,1)=left, (2,1)=right, (1,0)=up, (1,2)=down
    float p[16], aL[16], aR[16], aU[16], aD[16];
    #pragma unroll
    for (int h = 0; h < 4; ++h) {
        #pragma unroll
        for (int w = 0; w < 4; ++w) {
            int cl = h*4 + w;
            float rout = ro[cl*3 + 1];
            p[cl]  = ro[cl*3 + 2];
            aL[cl] = ((w > 0) ? ro[(cl-1)*3] : 0.0f) - rout;
            aR[cl] = ((w < 3) ? ro[(cl+1)*3] : 0.0f) - rout;
            aU[cl] = ((h > 0) ? ro[(cl-4)*3] : 0.0f) - rout;
            aD[cl] = ((h < 3) ? ro[(cl+4)*3] : 0.0f) - rout;
        }
    }

    // ---- K=20 value-iteration steps (all regs, static indexing) ----
    float V[16];
    #pragma unroll
    for (int k = 0; k < 16; ++k) V[k] = 0.0f;

    #pragma unroll 1
    for (int s = 0; s < 20; ++s) {
        float Vn[16];
        #pragma unroll
        for (int h = 0; h < 4; ++h) {
            #pragma unroll
            for (int w = 0; w < 4; ++w) {
                int cl = h*4 + w;
                float cL = (w > 0) ? fmaf(p[cl], V[cl-1], aL[cl]) : aL[cl];
                float cR = (w < 3) ? fmaf(p[cl], V[cl+1], aR[cl]) : aR[cl];
                float cU = (h > 0) ? fmaf(p[cl], V[cl-4], aU[cl]) : aU[cl];
                float cD = (h < 3) ? fmaf(p[cl], V[cl+4], aD[cl]) : aD[cl];
                Vn[cl] = fmaxf(fmaxf(V[cl], cL), fmaxf(fmaxf(cR, cU), cD));
            }
        }
        #pragma unroll
        for (int k = 0; k < 16; ++k) V[k] = Vn[k];
    }

    // ---- V to LDS (reuse words 0..15 of own row), sub_v features 27..35 ----
    #pragma unroll
    for (int k = 0; k < 16; ++k) my[k] = V[k];

    #pragma unroll
    for (int dh = 0; dh < 3; ++dh) {
        #pragma unroll
        for (int dw = 0; dw < 3; ++dw) {
            int r = ai + dh - 1, c = aj + dw - 1;
            bool ok = ((unsigned)r < 4u) && ((unsigned)c < 4u);
            int ba = ok ? (r*4 + c) : 0;
            float v = my[ba];
            if (!ok) v = 0.0f;
            int f = 27 + dh*3 + dw;
            lg0 = fmaf(v, LW[0*36+f], lg0);
            lg1 = fmaf(v, LW[1*36+f], lg1);
            lg2 = fmaf(v, LW[2*36+f], lg2);
            lg3 = fmaf(v, LW[3*36+f], lg3);
        }
    }

    // ---- coalesced float4 store ----
    reinterpret_cast<float4*>(out)[b] = make_float4(lg0, lg1, lg2, lg3);
}

extern "C" void kernel_launch(void* const* d_in, const int* in_sizes, int n_in,
                              void* d_out, int out_size, void* d_ws, size_t ws_size,
                              hipStream_t stream) {
    const float* obs  = (const float*)d_in[0];
    const float* PhiW = (const float*)d_in[1];
    const float* Phib = (const float*)d_in[2];
    const float* LW   = (const float*)d_in[3];
    const float* Lb   = (const float*)d_in[4];
    float* out = (float*)d_out;

    const int Btot = in_sizes[0] / 48;   // 1,000,000
    const int grid = (Btot + BT - 1) / BT;
    hipLaunchKernelGGL(vin_kernel, dim3(grid), dim3(BT), 0, stream,
                       obs, PhiW, Phib, LW, Lb, out, Btot);
}

// Round 2
// 73.967 us; speedup vs baseline: 1.5846x; 1.5846x over previous
//
#include <hip/hip_runtime.h>
#include <hip/hip_bf16.h>

#define BT 256           // 4 waves per block
#define WREG 13312       // per-wave LDS region bytes (64 rows x 208 B ro area; bf16 A-area overlays start)
// A-area: 64 rows x 144 B (72 shorts: 48 data + 16 zero-pad K, 8 unused)
// ro-area: 64 rows x 208 B (52 f32: 48 ro values + 4 pad)

typedef __attribute__((ext_vector_type(8))) short short8;
typedef __attribute__((ext_vector_type(4))) float f32x4;

__device__ inline short f2b(float x) {
    return __builtin_bit_cast(short, __float2bfloat16(x));
}
__device__ inline float b2f(short s) {
    unsigned u = ((unsigned)(unsigned short)s) << 16;
    return __builtin_bit_cast(float, u);
}
__device__ inline short8 pack8(float4 a, float4 b) {
    short8 r;
    r[0] = f2b(a.x); r[1] = f2b(a.y); r[2] = f2b(a.z); r[3] = f2b(a.w);
    r[4] = f2b(b.x); r[5] = f2b(b.y); r[6] = f2b(b.z); r[7] = f2b(b.w);
    return r;
}

__global__ __launch_bounds__(BT, 3) void vin_kernel(
    const float* __restrict__ obs,
    const float* __restrict__ PhiW,
    const float* __restrict__ Phib,
    const float* __restrict__ LW,
    const float* __restrict__ Lb,
    float* __restrict__ out, int Btot)
{
    __shared__ __align__(16) char smem[4 * WREG];   // 53248 B -> 3 blocks/CU
    const int tid  = threadIdx.x;
    const int lane = tid & 63;
    const int wid  = tid >> 6;
    const int b    = blockIdx.x * BT + tid;
    // Btot % 64 == 0 (1e6 = 15625 waves), so waves are entirely in or out.
    // No barriers anywhere -> early return is safe.
    if (b >= Btot) return;

    char* wbase = smem + wid * WREG;
    const int jn = lane & 15;   // col-in-tile / row-in-tile (A) index
    const int g  = lane >> 4;   // lane quarter-group

    // ---- phase 0: load obs row (48 f32, 12x float4, coalesced) ----
    float o[48];
    {
        const float4* g4 = reinterpret_cast<const float4*>(obs + (size_t)b * 48);
        #pragma unroll
        for (int q = 0; q < 12; ++q) {
            float4 t = g4[q];
            o[4*q+0] = t.x; o[4*q+1] = t.y; o[4*q+2] = t.z; o[4*q+3] = t.w;
        }
    }

    // ---- agent index from exact f32 (channel 1 is one-hot) ----
    int idx = 5;
    #pragma unroll
    for (int k = 15; k >= 0; --k)
        if (o[k*3+1] != 0.0f) idx = k;
    const int ai = idx >> 2;
    const int aj = idx & 3;

    // ---- B-fragments: PhiW^T tiles straight from global (L2-hot), bf16 ----
    // B[k][j] = PhiW[j*48+k]; lane holds col j=16n+jn, k = kbase + g*8 .. +7
    short8 bfrag[3][2];
    #pragma unroll
    for (int n = 0; n < 3; ++n) {
        const float* wrow = PhiW + (16*n + jn) * 48;
        float4 q0 = *reinterpret_cast<const float4*>(wrow + 8*g);
        float4 q1 = *reinterpret_cast<const float4*>(wrow + 8*g + 4);
        bfrag[n][0] = pack8(q0, q1);
        short8 z = {0,0,0,0,0,0,0,0};
        if (g < 2) {   // k = 32+8g .. +7 valid only for g<2; k>=48 is zero pad
            float4 q2 = *reinterpret_cast<const float4*>(wrow + 32 + 8*g);
            float4 q3 = *reinterpret_cast<const float4*>(wrow + 36 + 8*g);
            z = pack8(q2, q3);
        }
        bfrag[n][1] = z;
    }

    // ---- write own obs row to A-area as bf16, K zero-padded to 64 ----
    {
        short8* arow = reinterpret_cast<short8*>(wbase + lane * 144);
        #pragma unroll
        for (int t = 0; t < 6; ++t) {
            short8 v;
            #pragma unroll
            for (int e = 0; e < 8; ++e) v[e] = f2b(o[t*8 + e]);
            arow[t] = v;
        }
        short8 z = {0,0,0,0,0,0,0,0};
        arow[6] = z; arow[7] = z;   // k = 48..63 zeros
    }

    // ---- sub_state gather (features 0..26) from own bf16 row ----
    float lg0 = Lb[0], lg1 = Lb[1], lg2 = Lb[2], lg3 = Lb[3];
    {
        const short* myobs = reinterpret_cast<const short*>(wbase + lane * 144);
        #pragma unroll
        for (int dh = 0; dh < 3; ++dh) {
            #pragma unroll
            for (int dw = 0; dw < 3; ++dw) {
                int r = ai + dh - 1, c = aj + dw - 1;
                bool ok = ((unsigned)r < 4u) && ((unsigned)c < 4u);
                int ba = ok ? (r*4 + c) * 3 : 0;
                float s0 = b2f(myobs[ba+0]);
                float s1 = b2f(myobs[ba+1]);
                float s2 = b2f(myobs[ba+2]);
                if (!ok) { s0 = 0.f; s1 = 0.f; s2 = 0.f; }
                int f = (dh*3 + dw) * 3;
                lg0 = fmaf(s0, LW[0*36+f], fmaf(s1, LW[0*36+f+1], fmaf(s2, LW[0*36+f+2], lg0)));
                lg1 = fmaf(s0, LW[1*36+f], fmaf(s1, LW[1*36+f+1], fmaf(s2, LW[1*36+f+2], lg1)));
                lg2 = fmaf(s0, LW[2*36+f], fmaf(s1, LW[2*36+f+1], fmaf(s2, LW[2*36+f+2], lg2)));
                lg3 = fmaf(s0, LW[3*36+f], fmaf(s1, LW[3*36+f+1], fmaf(s2, LW[3*36+f+2], lg3)));
            }
        }
    }

    // ---- A-fragments: lane reads row m*16+jn, k = 32t + g*8 .. +7 ----
    short8 afrag[4][2];
    #pragma unroll
    for (int m = 0; m < 4; ++m) {
        const char* rp = wbase + (m*16 + jn) * 144;
        afrag[m][0] = *reinterpret_cast<const short8*>(rp + 16*g);
        afrag[m][1] = *reinterpret_cast<const short8*>(rp + 64 + 16*g);
    }

    // ---- 24 MFMAs: acc[m][n] over K=64 (zero-padded) ----
    f32x4 acc[4][3];
    #pragma unroll
    for (int m = 0; m < 4; ++m)
        #pragma unroll
        for (int n = 0; n < 3; ++n)
            acc[m][n] = (f32x4){0.f, 0.f, 0.f, 0.f};
    #pragma unroll
    for (int n = 0; n < 3; ++n)
        #pragma unroll
        for (int m = 0; m < 4; ++m) {
            acc[m][n] = __builtin_amdgcn_mfma_f32_16x16x32_bf16(afrag[m][0], bfrag[n][0], acc[m][n], 0, 0, 0);
            acc[m][n] = __builtin_amdgcn_mfma_f32_16x16x32_bf16(afrag[m][1], bfrag[n][1], acc[m][n], 0, 0, 0);
        }

    // A-area reads complete before ro-area writes overwrite the overlay.
    asm volatile("s_waitcnt lgkmcnt(0)" ::: "memory");
    __builtin_amdgcn_sched_barrier(0);

    // ---- scatter D to ro-area: lane holds col 16n+jn, rows m*16+g*4+r ----
    #pragma unroll
    for (int m = 0; m < 4; ++m)
        #pragma unroll
        for (int n = 0; n < 3; ++n)
            #pragma unroll
            for (int r = 0; r < 4; ++r) {
                int row = m*16 + g*4 + r;
                reinterpret_cast<float*>(wbase + row * 208)[n*16 + jn] = acc[m][n][r];
            }

    // all wave's scatter-writes complete before per-sample readback
    asm volatile("s_waitcnt lgkmcnt(0)" ::: "memory");
    __builtin_amdgcn_sched_barrier(0);

    // ---- read back own ro row (48 f32) + add bias ----
    float ro[48];
    {
        const char* myrow = wbase + lane * 208;
        #pragma unroll
        for (int q = 0; q < 12; ++q) {
            f32x4 t = *reinterpret_cast<const f32x4*>(myrow + q * 16);
            ro[4*q+0] = t[0] + Phib[4*q+0];
            ro[4*q+1] = t[1] + Phib[4*q+1];
            ro[4*q+2] = t[2] + Phib[4*q+2];
            ro[4*q+3] = t[3] + Phib[4*q+3];
        }
    }

    // ---- VI constants: pc, per-direction (rin_neighbor - rout) ----
    float pc[16], aL[16], aR[16], aU[16], aD[16];
    #pragma unroll
    for (int h = 0; h < 4; ++h)
        #pragma unroll
        for (int w = 0; w < 4; ++w) {
            int cl = h*4 + w;
            float rout = ro[cl*3 + 1];
            pc[cl] = ro[cl*3 + 2];
            aL[cl] = ((w > 0) ? ro[(cl-1)*3] : 0.0f) - rout;
            aR[cl] = ((w < 3) ? ro[(cl+1)*3] : 0.0f) - rout;
            aU[cl] = ((h > 0) ? ro[(cl-4)*3] : 0.0f) - rout;
            aD[cl] = ((h < 3) ? ro[(cl+4)*3] : 0.0f) - rout;
        }

    // ---- K=20 VI steps, all registers, static indexing ----
    float V[16];
    #pragma unroll
    for (int k = 0; k < 16; ++k) V[k] = 0.0f;

    #pragma unroll 1
    for (int s = 0; s < 20; ++s) {
        float Vn[16];
        #pragma unroll
        for (int h = 0; h < 4; ++h)
            #pragma unroll
            for (int w = 0; w < 4; ++w) {
                int cl = h*4 + w;
                float cL = (w > 0) ? fmaf(pc[cl], V[cl-1], aL[cl]) : aL[cl];
                float cR = (w < 3) ? fmaf(pc[cl], V[cl+1], aR[cl]) : aR[cl];
                float cU = (h > 0) ? fmaf(pc[cl], V[cl-4], aU[cl]) : aU[cl];
                float cD = (h < 3) ? fmaf(pc[cl], V[cl+4], aD[cl]) : aD[cl];
                Vn[cl] = fmaxf(fmaxf(V[cl], cL), fmaxf(fmaxf(cR, cU), cD));
            }
        #pragma unroll
        for (int k = 0; k < 16; ++k) V[k] = Vn[k];
    }

    // ---- V to own ro row words 0..15, then dynamic 3x3 gather ----
    {
        char* myrow = wbase + lane * 208;
        #pragma unroll
        for (int q = 0; q < 4; ++q)
            *reinterpret_cast<f32x4*>(myrow + q * 16) =
                (f32x4){V[4*q+0], V[4*q+1], V[4*q+2], V[4*q+3]};
    }
    asm volatile("s_waitcnt lgkmcnt(0)" ::: "memory");
    __builtin_amdgcn_sched_barrier(0);
    {
        const float* myv = reinterpret_cast<const float*>(wbase + lane * 208);
        #pragma unroll
        for (int dh = 0; dh < 3; ++dh)
            #pragma unroll
            for (int dw = 0; dw < 3; ++dw) {
                int r = ai + dh - 1, c = aj + dw - 1;
                bool ok = ((unsigned)r < 4u) && ((unsigned)c < 4u);
                int ba = ok ? (r*4 + c) : 0;
                float v = myv[ba];
                if (!ok) v = 0.0f;
                int f = 27 + dh*3 + dw;
                lg0 = fmaf(v, LW[0*36+f], lg0);
                lg1 = fmaf(v, LW[1*36+f], lg1);
                lg2 = fmaf(v, LW[2*36+f], lg2);
                lg3 = fmaf(v, LW[3*36+f], lg3);
            }
    }

    reinterpret_cast<float4*>(out)[b] = make_float4(lg0, lg1, lg2, lg3);
}

extern "C" void kernel_launch(void* const* d_in, const int* in_sizes, int n_in,
                              void* d_out, int out_size, void* d_ws, size_t ws_size,
                              hipStream_t stream) {
    const float* obs  = (const float*)d_in[0];
    const float* PhiW = (const float*)d_in[1];
    const float* Phib = (const float*)d_in[2];
    const float* LW   = (const float*)d_in[3];
    const float* Lb   = (const float*)d_in[4];
    float* out = (float*)d_out;

    const int Btot = in_sizes[0] / 48;   // 1,000,000
    const int grid = (Btot + BT - 1) / BT;
    hipLaunchKernelGGL(vin_kernel, dim3(grid), dim3(BT), 0, stream,
                       obs, PhiW, Phib, LW, Lb, out, Btot);
}